// Round 1
// baseline (3034.799 us; speedup 1.0000x reference)
//
#include <hip/hip_runtime.h>

// Problem constants
constexpr int B_ = 32, S_ = 512, D_ = 1024, H_ = 16, DH_ = 64, HD_ = 1024;
constexpr int M_ = B_ * S_;                 // 16384
constexpr float EPS_ = 1e-7f;
constexpr float INV_TEMP_ = 10.0f;          // 1/0.1

__device__ __forceinline__ float sigm(float x) { return 1.0f / (1.0f + __expf(-x)); }

// ---------------------------------------------------------------------------
// Fused concrete-dropout GEMM:  C = cd(A, p, U) @ W   (optionally ReLU)
// A,U: [M,1024], W: [1024,1024], C: [M,1024].  BM=BN=128, BK=16, 256 thr, 8x8/thr.
// ---------------------------------------------------------------------------
template<bool RELU>
__global__ __launch_bounds__(256)
void cd_gemm_kernel(const float* __restrict__ A, const float* __restrict__ U,
                    const float* __restrict__ W, const float* __restrict__ plp,
                    float* __restrict__ C)
{
    const int m0 = blockIdx.y * 128;
    const int n0 = blockIdx.x * 128;
    const int tid = threadIdx.x;
    const int tr = tid >> 4, tc = tid & 15;

    __shared__ float AsT[16][132];   // transposed A tile (k-major), padded
    __shared__ float Bs[16][132];    // B tile (k-major), padded

    const float pl = *plp;
    const float p = sigm(pl);
    const float c0 = __logf(p + EPS_) - __logf(1.0f - p + EPS_);
    const float inv1mp = 1.0f / (1.0f - p);

    float acc[8][8];
#pragma unroll
    for (int i = 0; i < 8; ++i)
#pragma unroll
        for (int j = 0; j < 8; ++j) acc[i][j] = 0.0f;

    for (int k0 = 0; k0 < 1024; k0 += 16) {
        __syncthreads();
        // stage A (2048 floats = 512 float4, 2 per thread) with concrete dropout
#pragma unroll
        for (int ii = 0; ii < 2; ++ii) {
            int idx = tid + ii * 256;
            int r = idx >> 2, c4 = idx & 3;
            size_t g = (size_t)(m0 + r) * 1024 + k0 + c4 * 4;
            float4 av = *(const float4*)(A + g);
            float4 uv = *(const float4*)(U + g);
            float a4[4] = {av.x, av.y, av.z, av.w};
            float u4[4] = {uv.x, uv.y, uv.z, uv.w};
#pragma unroll
            for (int t = 0; t < 4; ++t) {
                float lt = (c0 + __logf(u4[t] + EPS_) - __logf(1.0f - u4[t] + EPS_)) * INV_TEMP_;
                float dpr = sigm(lt);
                AsT[c4 * 4 + t][r] = a4[t] * (1.0f - dpr) * inv1mp;
            }
        }
        // stage B
#pragma unroll
        for (int ii = 0; ii < 2; ++ii) {
            int idx = tid + ii * 256;
            int r = idx >> 5, c4 = idx & 31;
            float4 wv = *(const float4*)(W + (size_t)(k0 + r) * 1024 + n0 + c4 * 4);
            *(float4*)&Bs[r][c4 * 4] = wv;
        }
        __syncthreads();
#pragma unroll
        for (int kk = 0; kk < 16; ++kk) {
            float4 a0 = *(float4*)&AsT[kk][tr * 8];
            float4 a1 = *(float4*)&AsT[kk][tr * 8 + 4];
            float4 b0 = *(float4*)&Bs[kk][tc * 8];
            float4 b1 = *(float4*)&Bs[kk][tc * 8 + 4];
            float av8[8] = {a0.x, a0.y, a0.z, a0.w, a1.x, a1.y, a1.z, a1.w};
            float bv8[8] = {b0.x, b0.y, b0.z, b0.w, b1.x, b1.y, b1.z, b1.w};
#pragma unroll
            for (int i = 0; i < 8; ++i)
#pragma unroll
                for (int j = 0; j < 8; ++j)
                    acc[i][j] = fmaf(av8[i], bv8[j], acc[i][j]);
        }
    }
#pragma unroll
    for (int i = 0; i < 8; ++i) {
        float ov[8];
#pragma unroll
        for (int j = 0; j < 8; ++j) {
            float t = acc[i][j];
            ov[j] = RELU ? fmaxf(t, 0.0f) : t;
        }
        float* cp = C + (size_t)(m0 + tr * 8 + i) * 1024 + n0 + tc * 8;
        *(float4*)cp       = make_float4(ov[0], ov[1], ov[2], ov[3]);
        *(float4*)(cp + 4) = make_float4(ov[4], ov[5], ov[6], ov[7]);
    }
}

// ---------------------------------------------------------------------------
// Scores + mask + softmax -> alpha.  Block = (b,h, 32 x-rows), 512 thr (8 waves),
// each wave owns 4 rows; K panel streamed in 128-row LDS tiles, XOR-swizzled.
// ---------------------------------------------------------------------------
__global__ __launch_bounds__(512)
void attn_softmax_kernel(const float* __restrict__ qg, const float* __restrict__ kg,
                         const int* __restrict__ lengths, float* __restrict__ alpha)
{
    const int bh = blockIdx.y;
    const int b = bh >> 4, h = bh & 15;
    const int x0 = blockIdx.x * 32;
    const int tid = threadIdx.x;
    const int w = tid >> 6, lane = tid & 63;
    const int len = lengths[b];

    __shared__ float qs[32][64];
    __shared__ float ks[128][64];   // float4 slots XOR-swizzled by (row & 15)

    {   // stage q rows for this block: 2048 floats = 512 float4, 1 per thread
        int r = tid >> 4, c4 = tid & 15;
        float4 qv = *(const float4*)(qg + ((size_t)(b * 512 + x0 + r) * 16 + h) * 64 + c4 * 4);
        *(float4*)&qs[r][c4 * 4] = qv;
    }

    float acc[4][8];
#pragma unroll
    for (int r = 0; r < 4; ++r)
#pragma unroll
        for (int c = 0; c < 8; ++c) acc[r][c] = 0.0f;

    for (int yt = 0; yt < 4; ++yt) {
        __syncthreads();
        // stage 128 k-rows: 8192 floats = 2048 float4, 4 per thread
#pragma unroll
        for (int ii = 0; ii < 4; ++ii) {
            int idx = tid + ii * 512;
            int r = idx >> 4, c4 = idx & 15;
            float4 kv = *(const float4*)(kg + ((size_t)(b * 512 + yt * 128 + r) * 16 + h) * 64 + c4 * 4);
            int cs = c4 ^ (r & 15);
            *(float4*)&ks[r][cs * 4] = kv;
        }
        __syncthreads();
#pragma unroll
        for (int f = 0; f < 16; ++f) {
            float4 q0 = *(float4*)&qs[w * 4 + 0][f * 4];
            float4 q1 = *(float4*)&qs[w * 4 + 1][f * 4];
            float4 q2 = *(float4*)&qs[w * 4 + 2][f * 4];
            float4 q3 = *(float4*)&qs[w * 4 + 3][f * 4];
#pragma unroll
            for (int jj = 0; jj < 2; ++jj) {
                int y = jj * 64 + lane;
                float4 kv = *(float4*)&ks[y][((f ^ (y & 15)) * 4)];
                int c = yt * 2 + jj;
                acc[0][c] += q0.x * kv.x + q0.y * kv.y + q0.z * kv.z + q0.w * kv.w;
                acc[1][c] += q1.x * kv.x + q1.y * kv.y + q1.z * kv.z + q1.w * kv.w;
                acc[2][c] += q2.x * kv.x + q2.y * kv.y + q2.z * kv.z + q2.w * kv.w;
                acc[3][c] += q3.x * kv.x + q3.y * kv.y + q3.z * kv.z + q3.w * kv.w;
            }
        }
    }

#pragma unroll
    for (int r = 0; r < 4; ++r) {
        int x = x0 + w * 4 + r;
        bool vx = (x <= len);
        float e[8];
        float m = -3.4e38f;
#pragma unroll
        for (int c = 0; c < 8; ++c) {
            int y = c * 64 + lane;
            e[c] = (vx && (y <= len)) ? acc[r][c] * 0.125f : -1e10f;
            m = fmaxf(m, e[c]);
        }
#pragma unroll
        for (int off = 32; off > 0; off >>= 1) m = fmaxf(m, __shfl_xor(m, off));
        float ssum = 0.0f;
#pragma unroll
        for (int c = 0; c < 8; ++c) { e[c] = __expf(e[c] - m); ssum += e[c]; }
#pragma unroll
        for (int off = 32; off > 0; off >>= 1) ssum += __shfl_xor(ssum, off);
        float inv = 1.0f / ssum;
        float* ap = alpha + ((size_t)bh * 512 + x) * 512;
#pragma unroll
        for (int c = 0; c < 8; ++c) ap[c * 64 + lane] = e[c] * inv;
    }
}

// ---------------------------------------------------------------------------
// PV: attn_out[b,x,h,:] = alpha[b,h,x,:] @ v[b,:,h,:].
// Block = (x-chunk of 256, bh). BM=256, N=64, BK=32, 256 thr, 8x8/thr.
// ---------------------------------------------------------------------------
__global__ __launch_bounds__(256)
void pv_kernel(const float* __restrict__ alpha, const float* __restrict__ vg,
               float* __restrict__ ao)
{
    const int bh = blockIdx.y;
    const int b = bh >> 4, h = bh & 15;
    const int x0 = blockIdx.x * 256;
    const int tid = threadIdx.x;
    const int tr = tid >> 3, tc = tid & 7;

    __shared__ float AsT[32][260];  // alpha tile transposed (y-major), padded
    __shared__ float Bs[32][64];    // v tile

    float acc[8][8];
#pragma unroll
    for (int i = 0; i < 8; ++i)
#pragma unroll
        for (int j = 0; j < 8; ++j) acc[i][j] = 0.0f;

    const float* Ab = alpha + ((size_t)bh * 512 + x0) * 512;

    for (int y0 = 0; y0 < 512; y0 += 32) {
        __syncthreads();
        // stage alpha tile 256x32 transposed: 2048 float4, 8 per thread
#pragma unroll
        for (int ii = 0; ii < 8; ++ii) {
            int idx = tid + ii * 256;
            int r = idx >> 3, c4 = idx & 7;
            float4 av = *(const float4*)(Ab + (size_t)r * 512 + y0 + c4 * 4);
            AsT[c4 * 4 + 0][r] = av.x;
            AsT[c4 * 4 + 1][r] = av.y;
            AsT[c4 * 4 + 2][r] = av.z;
            AsT[c4 * 4 + 3][r] = av.w;
        }
        // stage v tile 32x64: 512 float4, 2 per thread
#pragma unroll
        for (int ii = 0; ii < 2; ++ii) {
            int idx = tid + ii * 256;
            int r = idx >> 4, c4 = idx & 15;
            float4 vv = *(const float4*)(vg + ((size_t)(b * 512 + y0 + r) * 16 + h) * 64 + c4 * 4);
            *(float4*)&Bs[r][c4 * 4] = vv;
        }
        __syncthreads();
#pragma unroll
        for (int kk = 0; kk < 32; ++kk) {
            float4 a0 = *(float4*)&AsT[kk][tr * 8];
            float4 a1 = *(float4*)&AsT[kk][tr * 8 + 4];
            float4 b0 = *(float4*)&Bs[kk][tc * 8];
            float4 b1 = *(float4*)&Bs[kk][tc * 8 + 4];
            float av8[8] = {a0.x, a0.y, a0.z, a0.w, a1.x, a1.y, a1.z, a1.w};
            float bv8[8] = {b0.x, b0.y, b0.z, b0.w, b1.x, b1.y, b1.z, b1.w};
#pragma unroll
            for (int i = 0; i < 8; ++i)
#pragma unroll
                for (int j = 0; j < 8; ++j)
                    acc[i][j] = fmaf(av8[i], bv8[j], acc[i][j]);
        }
    }
#pragma unroll
    for (int i = 0; i < 8; ++i) {
        float* cp = ao + ((size_t)(b * 512 + x0 + tr * 8 + i) * 16 + h) * 64 + tc * 8;
        *(float4*)cp       = make_float4(acc[i][0], acc[i][1], acc[i][2], acc[i][3]);
        *(float4*)(cp + 4) = make_float4(acc[i][4], acc[i][5], acc[i][6], acc[i][7]);
    }
}

// ---------------------------------------------------------------------------
extern "C" void kernel_launch(void* const* d_in, const int* in_sizes, int n_in,
                              void* d_out, int out_size, void* d_ws, size_t ws_size,
                              hipStream_t stream)
{
    const float* x       = (const float*)d_in[0];
    const int*   lengths = (const int*)d_in[1];
    const float* Wq      = (const float*)d_in[2];
    const float* Wk      = (const float*)d_in[3];
    const float* Wv      = (const float*)d_in[4];
    const float* Wo      = (const float*)d_in[5];
    const float* pl      = (const float*)d_in[6];
    const float* nq      = (const float*)d_in[7];
    const float* nk      = (const float*)d_in[8];
    const float* nv      = (const float*)d_in[9];
    const float* no      = (const float*)d_in[10];

    float* outp  = (float*)d_out;                       // [B,S,D] = 16777216 floats
    float* alpha = outp + (size_t)M_ * D_;              // [B,H,S,S]

    const size_t chunk = (size_t)M_ * HD_;              // 16777216 floats
    float* q  = (float*)d_ws;
    float* k  = q + chunk;
    float* v  = k + chunk;
    float* ao = q;                                      // alias: q dead after softmax

    dim3 gemm_grid(8, 128), gemm_blk(256);
    cd_gemm_kernel<false><<<gemm_grid, gemm_blk, 0, stream>>>(x, nq, Wq, pl + 0, q);
    cd_gemm_kernel<false><<<gemm_grid, gemm_blk, 0, stream>>>(x, nk, Wk, pl + 1, k);
    cd_gemm_kernel<false><<<gemm_grid, gemm_blk, 0, stream>>>(x, nv, Wv, pl + 2, v);

    attn_softmax_kernel<<<dim3(16, B_ * H_), 512, 0, stream>>>(q, k, lengths, alpha);

    pv_kernel<<<dim3(2, B_ * H_), 256, 0, stream>>>(alpha, v, ao);

    cd_gemm_kernel<true><<<gemm_grid, gemm_blk, 0, stream>>>(ao, no, Wo, pl + 3, outp);
}

// Round 2
// 1038.195 us; speedup vs baseline: 2.9231x; 2.9231x over previous
//
#include <hip/hip_runtime.h>

// Problem constants
constexpr int B_ = 32, S_ = 512, D_ = 1024, H_ = 16, DH_ = 64, HD_ = 1024;
constexpr int M_ = B_ * S_;                 // 16384
constexpr float EPS_ = 1e-7f;
constexpr float INV_TEMP_ = 10.0f;          // 1/0.1

typedef __attribute__((ext_vector_type(8))) short bf16x8;
typedef __attribute__((ext_vector_type(4))) float f32x4;

__device__ __forceinline__ float sigm(float x) { return 1.0f / (1.0f + __expf(-x)); }

__device__ __forceinline__ unsigned short f2bf(float f) {
    unsigned u = __float_as_uint(f);
    unsigned r = (u + 0x7FFFu + ((u >> 16) & 1u)) >> 16;   // RNE
    return (unsigned short)r;
}

#define GLL16(gp, lp) __builtin_amdgcn_global_load_lds( \
    (const __attribute__((address_space(1))) unsigned int*)(gp), \
    (__attribute__((address_space(3))) unsigned int*)(lp), 16, 0, 0)

// ---------------------------------------------------------------------------
// Concrete-dropout + bf16 cast for q/k/v inputs (reads x once).
// 8 elems/thread, fully vectorized.
// ---------------------------------------------------------------------------
__global__ __launch_bounds__(256)
void cd_cast3_kernel(const float* __restrict__ x,
                     const float* __restrict__ nq, const float* __restrict__ nk,
                     const float* __restrict__ nv, const float* __restrict__ pl,
                     unsigned short* __restrict__ aq, unsigned short* __restrict__ ak,
                     unsigned short* __restrict__ av)
{
    size_t i0 = ((size_t)blockIdx.x * 256 + threadIdx.x) * 8;

    float c0[3], inv1mp[3];
#pragma unroll
    for (int j = 0; j < 3; ++j) {
        float p = sigm(pl[j]);
        c0[j] = __logf(p + EPS_) - __logf(1.0f - p + EPS_);
        inv1mp[j] = 1.0f / (1.0f - p);
    }

    float4 x0 = *(const float4*)(x + i0);
    float4 x1 = *(const float4*)(x + i0 + 4);
    float xv[8] = {x0.x, x0.y, x0.z, x0.w, x1.x, x1.y, x1.z, x1.w};

    const float* ns[3] = {nq, nk, nv};
    unsigned short* os[3] = {aq, ak, av};
#pragma unroll
    for (int j = 0; j < 3; ++j) {
        float4 u0 = *(const float4*)(ns[j] + i0);
        float4 u1 = *(const float4*)(ns[j] + i0 + 4);
        float uv[8] = {u0.x, u0.y, u0.z, u0.w, u1.x, u1.y, u1.z, u1.w};
        ushort out[8];
#pragma unroll
        for (int t = 0; t < 8; ++t) {
            float lt = (c0[j] + __logf(uv[t] + EPS_) - __logf(1.0f - uv[t] + EPS_)) * INV_TEMP_;
            float dpr = sigm(lt);
            out[t] = f2bf(xv[t] * (1.0f - dpr) * inv1mp[j]);
        }
        typedef __attribute__((ext_vector_type(8))) unsigned short us8;
        *(us8*)(os[j] + i0) = *(us8*)out;
    }
}

// Single-input variant (o-projection input).
__global__ __launch_bounds__(256)
void cd_cast1_kernel(const float* __restrict__ x, const float* __restrict__ u,
                     const float* __restrict__ pl, unsigned short* __restrict__ a)
{
    size_t i0 = ((size_t)blockIdx.x * 256 + threadIdx.x) * 8;
    float p = sigm(*pl);
    float c0 = __logf(p + EPS_) - __logf(1.0f - p + EPS_);
    float inv1mp = 1.0f / (1.0f - p);

    float4 x0 = *(const float4*)(x + i0);
    float4 x1 = *(const float4*)(x + i0 + 4);
    float4 u0 = *(const float4*)(u + i0);
    float4 u1 = *(const float4*)(u + i0 + 4);
    float xv[8] = {x0.x, x0.y, x0.z, x0.w, x1.x, x1.y, x1.z, x1.w};
    float uv[8] = {u0.x, u0.y, u0.z, u0.w, u1.x, u1.y, u1.z, u1.w};
    ushort out[8];
#pragma unroll
    for (int t = 0; t < 8; ++t) {
        float lt = (c0 + __logf(uv[t] + EPS_) - __logf(1.0f - uv[t] + EPS_)) * INV_TEMP_;
        float dpr = sigm(lt);
        out[t] = f2bf(xv[t] * (1.0f - dpr) * inv1mp);
    }
    typedef __attribute__((ext_vector_type(8))) unsigned short us8;
    *(us8*)(a + i0) = *(us8*)out;
}

// ---------------------------------------------------------------------------
// Weight cast + transpose: W[k][n] fp32 -> WT[n][k] bf16.  64x64 LDS tiles.
// ---------------------------------------------------------------------------
__global__ __launch_bounds__(256)
void wcast_t_kernel(const float* __restrict__ W, unsigned short* __restrict__ WT)
{
    __shared__ unsigned short t[64][72];
    int kb = blockIdx.y * 64;   // rows of W (k)
    int nb = blockIdx.x * 64;   // cols of W (n)
    int tid = threadIdx.x;
#pragma unroll
    for (int i = 0; i < 4; ++i) {
        int idx = tid + i * 256;
        int r = idx >> 4, c4 = idx & 15;
        float4 v = *(const float4*)(W + (size_t)(kb + r) * 1024 + nb + c4 * 4);
        t[c4 * 4 + 0][r] = f2bf(v.x);
        t[c4 * 4 + 1][r] = f2bf(v.y);
        t[c4 * 4 + 2][r] = f2bf(v.z);
        t[c4 * 4 + 3][r] = f2bf(v.w);
    }
    __syncthreads();
#pragma unroll
    for (int i = 0; i < 4; ++i) {
        int idx = tid + i * 256;
        int r = idx >> 4, c4 = idx & 15;
        ushort4 o;
        o.x = t[r][c4 * 4 + 0];
        o.y = t[r][c4 * 4 + 1];
        o.z = t[r][c4 * 4 + 2];
        o.w = t[r][c4 * 4 + 3];
        *(ushort4*)(WT + (size_t)(nb + r) * 1024 + kb + c4 * 4) = o;
    }
}

// ---------------------------------------------------------------------------
// bf16 MFMA GEMM (m97 structure): C[M][1024] fp32 = A[M][1024]bf16 @ BT[n][k]bf16^T
// BM=BN=128, BK=32, 256 thr (4 waves, 2x2), 4x4 16x16x32 fragments per wave.
// ---------------------------------------------------------------------------
template<bool RELU>
__global__ __launch_bounds__(256, 3)
void gemm_bf16_kernel(const unsigned short* __restrict__ A,
                      const unsigned short* __restrict__ BT,
                      float* __restrict__ C)
{
    __shared__ unsigned short As[128 * 32];
    __shared__ unsigned short Bs[128 * 32];

    // XCD-aware swizzle: nwg=1024, 128 per XCD chunk
    int flat = blockIdx.x;
    int swz = (flat & 7) * 128 + (flat >> 3);
    int ntile = swz & 7, mtile = swz >> 3;
    int m0 = mtile * 128, n0 = ntile * 128;

    int tid = threadIdx.x;
    int w = tid >> 6, lane = tid & 63;
    int wm = w >> 1, wn = w & 1;

    f32x4 acc[4][4];
#pragma unroll
    for (int m = 0; m < 4; ++m)
#pragma unroll
        for (int n = 0; n < 4; ++n) acc[m][n] = (f32x4){0.f, 0.f, 0.f, 0.f};

    // staging addresses: wave w stages rows [w*32, w*32+32) of each tile,
    // two 1KB global_load_lds per tile (16 rows each, lane covers 16B)
    const unsigned short* Ag = A + (size_t)(m0 + w * 32 + (lane >> 2)) * 1024 + (lane & 3) * 8;
    const unsigned short* Bg = BT + (size_t)(n0 + w * 32 + (lane >> 2)) * 1024 + (lane & 3) * 8;
    unsigned short* AsW = As + (w * 32) * 32;
    unsigned short* BsW = Bs + (w * 32) * 32;

    const int arow = wm * 64 + (lane & 15);
    const int brow = wn * 64 + (lane & 15);
    const int koff = (lane >> 4) * 8;

    for (int k0 = 0; k0 < 1024; k0 += 32) {
        __syncthreads();
        GLL16(Ag + k0,             AsW);
        GLL16(Ag + k0 + 16 * 1024, AsW + 16 * 32);
        GLL16(Bg + k0,             BsW);
        GLL16(Bg + k0 + 16 * 1024, BsW + 16 * 32);
        __syncthreads();

        bf16x8 afr[4], bfr[4];
#pragma unroll
        for (int m = 0; m < 4; ++m)
            afr[m] = *(const bf16x8*)&As[(arow + m * 16) * 32 + koff];
#pragma unroll
        for (int n = 0; n < 4; ++n)
            bfr[n] = *(const bf16x8*)&Bs[(brow + n * 16) * 32 + koff];
#pragma unroll
        for (int m = 0; m < 4; ++m)
#pragma unroll
            for (int n = 0; n < 4; ++n)
                acc[m][n] = __builtin_amdgcn_mfma_f32_16x16x32_bf16(afr[m], bfr[n], acc[m][n], 0, 0, 0);
    }

    // epilogue: C/D layout col=lane&15, row=(lane>>4)*4+j
    int cr = (lane >> 4) * 4, cc = lane & 15;
#pragma unroll
    for (int m = 0; m < 4; ++m)
#pragma unroll
        for (int n = 0; n < 4; ++n)
#pragma unroll
            for (int j = 0; j < 4; ++j) {
                int row = m0 + wm * 64 + m * 16 + cr + j;
                int col = n0 + wn * 64 + n * 16 + cc;
                float v = acc[m][n][j];
                C[(size_t)row * 1024 + col] = RELU ? fmaxf(v, 0.f) : v;
            }
}

// ---------------------------------------------------------------------------
// Scores + mask + softmax -> alpha (unchanged from R1, passed).
// ---------------------------------------------------------------------------
__global__ __launch_bounds__(512)
void attn_softmax_kernel(const float* __restrict__ qg, const float* __restrict__ kg,
                         const int* __restrict__ lengths, float* __restrict__ alpha)
{
    const int bh = blockIdx.y;
    const int b = bh >> 4, h = bh & 15;
    const int x0 = blockIdx.x * 32;
    const int tid = threadIdx.x;
    const int w = tid >> 6, lane = tid & 63;
    const int len = lengths[b];

    __shared__ float qs[32][64];
    __shared__ float ks[128][64];

    {
        int r = tid >> 4, c4 = tid & 15;
        float4 qv = *(const float4*)(qg + ((size_t)(b * 512 + x0 + r) * 16 + h) * 64 + c4 * 4);
        *(float4*)&qs[r][c4 * 4] = qv;
    }

    float acc[4][8];
#pragma unroll
    for (int r = 0; r < 4; ++r)
#pragma unroll
        for (int c = 0; c < 8; ++c) acc[r][c] = 0.0f;

    for (int yt = 0; yt < 4; ++yt) {
        __syncthreads();
#pragma unroll
        for (int ii = 0; ii < 4; ++ii) {
            int idx = tid + ii * 512;
            int r = idx >> 4, c4 = idx & 15;
            float4 kv = *(const float4*)(kg + ((size_t)(b * 512 + yt * 128 + r) * 16 + h) * 64 + c4 * 4);
            int cs = c4 ^ (r & 15);
            *(float4*)&ks[r][cs * 4] = kv;
        }
        __syncthreads();
#pragma unroll
        for (int f = 0; f < 16; ++f) {
            float4 q0 = *(float4*)&qs[w * 4 + 0][f * 4];
            float4 q1 = *(float4*)&qs[w * 4 + 1][f * 4];
            float4 q2 = *(float4*)&qs[w * 4 + 2][f * 4];
            float4 q3 = *(float4*)&qs[w * 4 + 3][f * 4];
#pragma unroll
            for (int jj = 0; jj < 2; ++jj) {
                int y = jj * 64 + lane;
                float4 kv = *(float4*)&ks[y][((f ^ (y & 15)) * 4)];
                int c = yt * 2 + jj;
                acc[0][c] += q0.x * kv.x + q0.y * kv.y + q0.z * kv.z + q0.w * kv.w;
                acc[1][c] += q1.x * kv.x + q1.y * kv.y + q1.z * kv.z + q1.w * kv.w;
                acc[2][c] += q2.x * kv.x + q2.y * kv.y + q2.z * kv.z + q2.w * kv.w;
                acc[3][c] += q3.x * kv.x + q3.y * kv.y + q3.z * kv.z + q3.w * kv.w;
            }
        }
    }

#pragma unroll
    for (int r = 0; r < 4; ++r) {
        int x = x0 + w * 4 + r;
        bool vx = (x <= len);
        float e[8];
        float m = -3.4e38f;
#pragma unroll
        for (int c = 0; c < 8; ++c) {
            int y = c * 64 + lane;
            e[c] = (vx && (y <= len)) ? acc[r][c] * 0.125f : -1e10f;
            m = fmaxf(m, e[c]);
        }
#pragma unroll
        for (int off = 32; off > 0; off >>= 1) m = fmaxf(m, __shfl_xor(m, off));
        float ssum = 0.0f;
#pragma unroll
        for (int c = 0; c < 8; ++c) { e[c] = __expf(e[c] - m); ssum += e[c]; }
#pragma unroll
        for (int off = 32; off > 0; off >>= 1) ssum += __shfl_xor(ssum, off);
        float inv = 1.0f / ssum;
        float* ap = alpha + ((size_t)bh * 512 + x) * 512;
#pragma unroll
        for (int c = 0; c < 8; ++c) ap[c * 64 + lane] = e[c] * inv;
    }
}

// ---------------------------------------------------------------------------
// PV (unchanged from R1, passed).
// ---------------------------------------------------------------------------
__global__ __launch_bounds__(256)
void pv_kernel(const float* __restrict__ alpha, const float* __restrict__ vg,
               float* __restrict__ ao)
{
    const int bh = blockIdx.y;
    const int b = bh >> 4, h = bh & 15;
    const int x0 = blockIdx.x * 256;
    const int tid = threadIdx.x;
    const int tr = tid >> 3, tc = tid & 7;

    __shared__ float AsT[32][260];
    __shared__ float Bs[32][64];

    float acc[8][8];
#pragma unroll
    for (int i = 0; i < 8; ++i)
#pragma unroll
        for (int j = 0; j < 8; ++j) acc[i][j] = 0.0f;

    const float* Ab = alpha + ((size_t)bh * 512 + x0) * 512;

    for (int y0 = 0; y0 < 512; y0 += 32) {
        __syncthreads();
#pragma unroll
        for (int ii = 0; ii < 8; ++ii) {
            int idx = tid + ii * 256;
            int r = idx >> 3, c4 = idx & 7;
            float4 av = *(const float4*)(Ab + (size_t)r * 512 + y0 + c4 * 4);
            AsT[c4 * 4 + 0][r] = av.x;
            AsT[c4 * 4 + 1][r] = av.y;
            AsT[c4 * 4 + 2][r] = av.z;
            AsT[c4 * 4 + 3][r] = av.w;
        }
#pragma unroll
        for (int ii = 0; ii < 2; ++ii) {
            int idx = tid + ii * 256;
            int r = idx >> 4, c4 = idx & 15;
            float4 vv = *(const float4*)(vg + ((size_t)(b * 512 + y0 + r) * 16 + h) * 64 + c4 * 4);
            *(float4*)&Bs[r][c4 * 4] = vv;
        }
        __syncthreads();
#pragma unroll
        for (int kk = 0; kk < 32; ++kk) {
            float4 a0 = *(float4*)&AsT[kk][tr * 8];
            float4 a1 = *(float4*)&AsT[kk][tr * 8 + 4];
            float4 b0 = *(float4*)&Bs[kk][tc * 8];
            float4 b1 = *(float4*)&Bs[kk][tc * 8 + 4];
            float av8[8] = {a0.x, a0.y, a0.z, a0.w, a1.x, a1.y, a1.z, a1.w};
            float bv8[8] = {b0.x, b0.y, b0.z, b0.w, b1.x, b1.y, b1.z, b1.w};
#pragma unroll
            for (int i = 0; i < 8; ++i)
#pragma unroll
                for (int j = 0; j < 8; ++j)
                    acc[i][j] = fmaf(av8[i], bv8[j], acc[i][j]);
        }
    }
#pragma unroll
    for (int i = 0; i < 8; ++i) {
        float* cp = ao + ((size_t)(b * 512 + x0 + tr * 8 + i) * 16 + h) * 64 + tc * 8;
        *(float4*)cp       = make_float4(acc[i][0], acc[i][1], acc[i][2], acc[i][3]);
        *(float4*)(cp + 4) = make_float4(acc[i][4], acc[i][5], acc[i][6], acc[i][7]);
    }
}

// ---------------------------------------------------------------------------
extern "C" void kernel_launch(void* const* d_in, const int* in_sizes, int n_in,
                              void* d_out, int out_size, void* d_ws, size_t ws_size,
                              hipStream_t stream)
{
    const float* x       = (const float*)d_in[0];
    const int*   lengths = (const int*)d_in[1];
    const float* Wq      = (const float*)d_in[2];
    const float* Wk      = (const float*)d_in[3];
    const float* Wv      = (const float*)d_in[4];
    const float* Wo      = (const float*)d_in[5];
    const float* pl      = (const float*)d_in[6];
    const float* nq      = (const float*)d_in[7];
    const float* nk      = (const float*)d_in[8];
    const float* nv      = (const float*)d_in[9];
    const float* no      = (const float*)d_in[10];

    float* outp   = (float*)d_out;                      // [B,S,D]
    float* alphaF = outp + (size_t)M_ * D_;             // [B,H,S,S] (134M floats)

    // bf16 staging buffers live in the alpha region (dead until softmax writes it)
    unsigned short* WTq = (unsigned short*)(alphaF);
    unsigned short* WTk = (unsigned short*)(alphaF + 524288);
    unsigned short* WTv = (unsigned short*)(alphaF + 1048576);
    unsigned short* Aq  = (unsigned short*)(alphaF + 1572864);
    unsigned short* Ak  = (unsigned short*)(alphaF + 9961472);
    unsigned short* Av  = (unsigned short*)(alphaF + 18350080);

    const size_t chunk = (size_t)M_ * HD_;              // 16.78M floats
    float* q  = (float*)d_ws;
    float* k  = q + chunk;
    float* v  = k + chunk;
    float* ao = q;                                      // q dead after softmax
    unsigned short* WTo = (unsigned short*)k;           // k dead after softmax
    unsigned short* Ao  = (unsigned short*)(k + 1048576);

    dim3 wgrid(16, 16), blk(256);
    wcast_t_kernel<<<wgrid, blk, 0, stream>>>(Wq, WTq);
    wcast_t_kernel<<<wgrid, blk, 0, stream>>>(Wk, WTk);
    wcast_t_kernel<<<wgrid, blk, 0, stream>>>(Wv, WTv);

    cd_cast3_kernel<<<8192, blk, 0, stream>>>(x, nq, nk, nv, pl, Aq, Ak, Av);

    gemm_bf16_kernel<false><<<1024, blk, 0, stream>>>(Aq, WTq, q);
    gemm_bf16_kernel<false><<<1024, blk, 0, stream>>>(Ak, WTk, k);
    gemm_bf16_kernel<false><<<1024, blk, 0, stream>>>(Av, WTv, v);

    attn_softmax_kernel<<<dim3(16, B_ * H_), 512, 0, stream>>>(q, k, lengths, alphaF);

    pv_kernel<<<dim3(2, B_ * H_), 256, 0, stream>>>(alphaF, v, ao);

    wcast_t_kernel<<<wgrid, blk, 0, stream>>>(Wo, WTo);
    cd_cast1_kernel<<<8192, blk, 0, stream>>>(ao, no, pl + 3, Ao);

    gemm_bf16_kernel<true><<<1024, blk, 0, stream>>>(Ao, WTo, outp);
}

// Round 3
// 644.655 us; speedup vs baseline: 4.7076x; 1.6105x over previous
//
#include <hip/hip_runtime.h>

// Problem constants
constexpr int B_ = 32, S_ = 512, D_ = 1024, H_ = 16, DH_ = 64, HD_ = 1024;
constexpr int M_ = B_ * S_;                 // 16384
constexpr float EPS_ = 1e-7f;
constexpr float INV_TEMP_ = 10.0f;          // 1/0.1

typedef __attribute__((ext_vector_type(8))) short bf16x8;
typedef __attribute__((ext_vector_type(4))) float f32x4;
typedef __attribute__((ext_vector_type(8))) unsigned short us8;

__device__ __forceinline__ float sigm(float x) { return 1.0f / (1.0f + __expf(-x)); }

__device__ __forceinline__ unsigned short f2bf(float f) {
    unsigned u = __float_as_uint(f);
    unsigned r = (u + 0x7FFFu + ((u >> 16) & 1u)) >> 16;   // RNE
    return (unsigned short)r;
}

#define GLL16(gp, lp) __builtin_amdgcn_global_load_lds( \
    (const __attribute__((address_space(1))) unsigned int*)(gp), \
    (__attribute__((address_space(3))) unsigned int*)(lp), 16, 0, 0)

// LDS fragment read with XOR swizzle: element = row*64 + ((k>>3 ^ (row&7))*8)
__device__ __forceinline__ bf16x8 ldsfrag64(const unsigned short* base, int row, int k) {
    int slot = ((k >> 3) ^ (row & 7)) << 3;
    return *(const bf16x8*)(base + row * 64 + slot);
}

// ---------------------------------------------------------------------------
// Concrete-dropout + bf16 cast for q/k/v inputs (reads x once).
// ---------------------------------------------------------------------------
__global__ __launch_bounds__(256)
void cd_cast3_kernel(const float* __restrict__ x,
                     const float* __restrict__ nq, const float* __restrict__ nk,
                     const float* __restrict__ nv, const float* __restrict__ pl,
                     unsigned short* __restrict__ aq, unsigned short* __restrict__ ak,
                     unsigned short* __restrict__ av)
{
    size_t i0 = ((size_t)blockIdx.x * 256 + threadIdx.x) * 8;

    float c0[3], inv1mp[3];
#pragma unroll
    for (int j = 0; j < 3; ++j) {
        float p = sigm(pl[j]);
        c0[j] = __logf(p + EPS_) - __logf(1.0f - p + EPS_);
        inv1mp[j] = 1.0f / (1.0f - p);
    }

    float4 x0 = *(const float4*)(x + i0);
    float4 x1 = *(const float4*)(x + i0 + 4);
    float xv[8] = {x0.x, x0.y, x0.z, x0.w, x1.x, x1.y, x1.z, x1.w};

    const float* ns[3] = {nq, nk, nv};
    unsigned short* os[3] = {aq, ak, av};
#pragma unroll
    for (int j = 0; j < 3; ++j) {
        float4 u0 = *(const float4*)(ns[j] + i0);
        float4 u1 = *(const float4*)(ns[j] + i0 + 4);
        float uv[8] = {u0.x, u0.y, u0.z, u0.w, u1.x, u1.y, u1.z, u1.w};
        ushort out[8];
#pragma unroll
        for (int t = 0; t < 8; ++t) {
            float lt = (c0[j] + __logf(uv[t] + EPS_) - __logf(1.0f - uv[t] + EPS_)) * INV_TEMP_;
            float dpr = sigm(lt);
            out[t] = f2bf(xv[t] * (1.0f - dpr) * inv1mp[j]);
        }
        *(us8*)(os[j] + i0) = *(us8*)out;
    }
}

__global__ __launch_bounds__(256)
void cd_cast1_kernel(const float* __restrict__ x, const float* __restrict__ u,
                     const float* __restrict__ pl, unsigned short* __restrict__ a)
{
    size_t i0 = ((size_t)blockIdx.x * 256 + threadIdx.x) * 8;
    float p = sigm(*pl);
    float c0 = __logf(p + EPS_) - __logf(1.0f - p + EPS_);
    float inv1mp = 1.0f / (1.0f - p);

    float4 x0 = *(const float4*)(x + i0);
    float4 x1 = *(const float4*)(x + i0 + 4);
    float4 u0 = *(const float4*)(u + i0);
    float4 u1 = *(const float4*)(u + i0 + 4);
    float xv[8] = {x0.x, x0.y, x0.z, x0.w, x1.x, x1.y, x1.z, x1.w};
    float uv[8] = {u0.x, u0.y, u0.z, u0.w, u1.x, u1.y, u1.z, u1.w};
    ushort out[8];
#pragma unroll
    for (int t = 0; t < 8; ++t) {
        float lt = (c0 + __logf(uv[t] + EPS_) - __logf(1.0f - uv[t] + EPS_)) * INV_TEMP_;
        float dpr = sigm(lt);
        out[t] = f2bf(xv[t] * (1.0f - dpr) * inv1mp);
    }
    *(us8*)(a + i0) = *(us8*)out;
}

// ---------------------------------------------------------------------------
// Weight cast + transpose: W[k][n] fp32 -> WT[n][k] bf16.
// ---------------------------------------------------------------------------
__global__ __launch_bounds__(256)
void wcast_t_kernel(const float* __restrict__ W, unsigned short* __restrict__ WT)
{
    __shared__ unsigned short t[64][72];
    int kb = blockIdx.y * 64;
    int nb = blockIdx.x * 64;
    int tid = threadIdx.x;
#pragma unroll
    for (int i = 0; i < 4; ++i) {
        int idx = tid + i * 256;
        int r = idx >> 4, c4 = idx & 15;
        float4 v = *(const float4*)(W + (size_t)(kb + r) * 1024 + nb + c4 * 4);
        t[c4 * 4 + 0][r] = f2bf(v.x);
        t[c4 * 4 + 1][r] = f2bf(v.y);
        t[c4 * 4 + 2][r] = f2bf(v.z);
        t[c4 * 4 + 3][r] = f2bf(v.w);
    }
    __syncthreads();
#pragma unroll
    for (int i = 0; i < 4; ++i) {
        int idx = tid + i * 256;
        int r = idx >> 4, c4 = idx & 15;
        ushort4 o;
        o.x = t[r][c4 * 4 + 0];
        o.y = t[r][c4 * 4 + 1];
        o.z = t[r][c4 * 4 + 2];
        o.w = t[r][c4 * 4 + 3];
        *(ushort4*)(WT + (size_t)(nb + r) * 1024 + kb + c4 * 4) = o;
    }
}

// ---------------------------------------------------------------------------
// V transpose: vb[b,y,h,d] bf16 -> vT[b,h,d,y] bf16
// ---------------------------------------------------------------------------
__global__ __launch_bounds__(256)
void vtrans_kernel(const unsigned short* __restrict__ vb, unsigned short* __restrict__ vT)
{
    __shared__ unsigned short t[64][136];
    int bh = blockIdx.y, b = bh >> 4, h = bh & 15;
    int y0 = blockIdx.x * 128;
    int tid = threadIdx.x;
#pragma unroll
    for (int i = 0; i < 4; ++i) {
        int idx = tid + i * 256;
        int r = idx >> 3, d0 = (idx & 7) * 8;
        us8 v = *(const us8*)(vb + ((size_t)(b * 512 + y0 + r)) * 1024 + h * 64 + d0);
#pragma unroll
        for (int e = 0; e < 8; ++e) t[d0 + e][r] = v[e];
    }
    __syncthreads();
#pragma unroll
    for (int i = 0; i < 4; ++i) {
        int idx = tid + i * 256;
        int dr = idx >> 4, y4 = (idx & 15) * 8;
        us8 o = *(const us8*)&t[dr][y4];
        *(us8*)(vT + ((size_t)bh * 64 + dr) * 512 + y0 + y4) = o;
    }
}

// ---------------------------------------------------------------------------
// bf16 MFMA GEMM (m97 structure), templated output dtype.
// ---------------------------------------------------------------------------
template<bool RELU, bool BF16OUT>
__global__ __launch_bounds__(256, 3)
void gemm_bf16_kernel(const unsigned short* __restrict__ A,
                      const unsigned short* __restrict__ BT,
                      void* __restrict__ Cv)
{
    __shared__ unsigned short As[128 * 32];
    __shared__ unsigned short Bs[128 * 32];

    int flat = blockIdx.x;
    int swz = (flat & 7) * 128 + (flat >> 3);
    int ntile = swz & 7, mtile = swz >> 3;
    int m0 = mtile * 128, n0 = ntile * 128;

    int tid = threadIdx.x;
    int w = tid >> 6, lane = tid & 63;
    int wm = w >> 1, wn = w & 1;

    f32x4 acc[4][4];
#pragma unroll
    for (int m = 0; m < 4; ++m)
#pragma unroll
        for (int n = 0; n < 4; ++n) acc[m][n] = (f32x4){0.f, 0.f, 0.f, 0.f};

    const unsigned short* Ag = A + (size_t)(m0 + w * 32 + (lane >> 2)) * 1024 + (lane & 3) * 8;
    const unsigned short* Bg = BT + (size_t)(n0 + w * 32 + (lane >> 2)) * 1024 + (lane & 3) * 8;
    unsigned short* AsW = As + (w * 32) * 32;
    unsigned short* BsW = Bs + (w * 32) * 32;

    const int arow = wm * 64 + (lane & 15);
    const int brow = wn * 64 + (lane & 15);
    const int koff = (lane >> 4) * 8;

    for (int k0 = 0; k0 < 1024; k0 += 32) {
        __syncthreads();
        GLL16(Ag + k0,             AsW);
        GLL16(Ag + k0 + 16 * 1024, AsW + 16 * 32);
        GLL16(Bg + k0,             BsW);
        GLL16(Bg + k0 + 16 * 1024, BsW + 16 * 32);
        __syncthreads();

        bf16x8 afr[4], bfr[4];
#pragma unroll
        for (int m = 0; m < 4; ++m)
            afr[m] = *(const bf16x8*)&As[(arow + m * 16) * 32 + koff];
#pragma unroll
        for (int n = 0; n < 4; ++n)
            bfr[n] = *(const bf16x8*)&Bs[(brow + n * 16) * 32 + koff];
#pragma unroll
        for (int m = 0; m < 4; ++m)
#pragma unroll
            for (int n = 0; n < 4; ++n)
                acc[m][n] = __builtin_amdgcn_mfma_f32_16x16x32_bf16(afr[m], bfr[n], acc[m][n], 0, 0, 0);
    }

    int cr = (lane >> 4) * 4, cc = lane & 15;
#pragma unroll
    for (int m = 0; m < 4; ++m)
#pragma unroll
        for (int n = 0; n < 4; ++n)
#pragma unroll
            for (int j = 0; j < 4; ++j) {
                int row = m0 + wm * 64 + m * 16 + cr + j;
                int col = n0 + wn * 64 + n * 16 + cc;
                float v = acc[m][n][j];
                if (RELU) v = fmaxf(v, 0.f);
                if (BF16OUT) ((unsigned short*)Cv)[(size_t)row * 1024 + col] = f2bf(v);
                else         ((float*)Cv)[(size_t)row * 1024 + col] = v;
            }
}

// ---------------------------------------------------------------------------
// MFMA attention scores + mask + softmax -> alpha fp32.
// Block = (b,h, 64 q-rows), 256 thr (4 waves). Wave w owns rows [w*16,+16).
// K streamed in 64-row double-buffered LDS tiles.
// ---------------------------------------------------------------------------
__global__ __launch_bounds__(256, 2)
void attn_mfma_kernel(const unsigned short* __restrict__ qb,
                      const unsigned short* __restrict__ kb,
                      const int* __restrict__ lengths,
                      float* __restrict__ alpha)
{
    const int bh = blockIdx.y;
    const int b = bh >> 4, h = bh & 15;
    const int x0 = blockIdx.x * 64;
    const int tid = threadIdx.x;
    const int w = tid >> 6, lane = tid & 63;
    const int len = lengths[b];

    __shared__ unsigned short Qs[64 * 64];
    __shared__ unsigned short Ks[2][64 * 64];

    const int sr = lane >> 3;                    // row within 8-row chunk
    const int sc = ((lane & 7) ^ sr) * 8;        // pre-swizzled source col

    // stage Q (8 chunks of 8 rows; wave w does chunks 2w, 2w+1)
    {
        const size_t qbase = ((size_t)(b * 512 + x0)) * 1024 + h * 64;
#pragma unroll
        for (int i = 0; i < 2; ++i) {
            int c = w * 2 + i;
            GLL16(qb + qbase + (size_t)(c * 8 + sr) * 1024 + sc, Qs + c * 512);
        }
    }
    // stage K tile 0
    {
        const size_t kbase = ((size_t)(b * 512)) * 1024 + h * 64;
#pragma unroll
        for (int i = 0; i < 2; ++i) {
            int c = w * 2 + i;
            GLL16(kb + kbase + (size_t)(c * 8 + sr) * 1024 + sc, Ks[0] + c * 512);
        }
    }
    __syncthreads();

    const int qrow = w * 16 + (lane & 15);
    const int kof  = (lane >> 4) * 8;
    bf16x8 qf0 = ldsfrag64(Qs, qrow, kof);
    bf16x8 qf1 = ldsfrag64(Qs, qrow, kof + 32);

    f32x4 acc[32];
#pragma unroll
    for (int f = 0; f < 32; ++f) acc[f] = (f32x4){0.f, 0.f, 0.f, 0.f};

#pragma unroll
    for (int kt = 0; kt < 8; ++kt) {
        const unsigned short* cur = Ks[kt & 1];
        if (kt < 7) {
            const size_t kbase = ((size_t)(b * 512 + (kt + 1) * 64)) * 1024 + h * 64;
#pragma unroll
            for (int i = 0; i < 2; ++i) {
                int c = w * 2 + i;
                GLL16(kb + kbase + (size_t)(c * 8 + sr) * 1024 + sc, Ks[(kt + 1) & 1] + c * 512);
            }
        }
#pragma unroll
        for (int cf = 0; cf < 4; ++cf) {
            int krow = cf * 16 + (lane & 15);
            bf16x8 kf0 = ldsfrag64(cur, krow, kof);
            bf16x8 kf1 = ldsfrag64(cur, krow, kof + 32);
            acc[kt * 4 + cf] = __builtin_amdgcn_mfma_f32_16x16x32_bf16(qf0, kf0, acc[kt * 4 + cf], 0, 0, 0);
            acc[kt * 4 + cf] = __builtin_amdgcn_mfma_f32_16x16x32_bf16(qf1, kf1, acc[kt * 4 + cf], 0, 0, 0);
        }
        __syncthreads();
    }

    // softmax per row; C layout: row=(lane>>4)*4+j, col=lane&15 within each frag
    const int g = lane >> 4, li = lane & 15;
    const float scale = 0.125f;   // 1/sqrt(64)
#pragma unroll
    for (int j = 0; j < 4; ++j) {
        int x = x0 + w * 16 + g * 4 + j;
        bool vx = (x <= len);
        float m = -3.4e38f;
#pragma unroll
        for (int f = 0; f < 32; ++f) {
            int y = f * 16 + li;
            float s = (vx && (y <= len)) ? acc[f][j] * scale : -1e10f;
            acc[f][j] = s;
            m = fmaxf(m, s);
        }
#pragma unroll
        for (int off = 8; off > 0; off >>= 1) m = fmaxf(m, __shfl_xor(m, off));
        float ssum = 0.0f;
#pragma unroll
        for (int f = 0; f < 32; ++f) {
            float e = __expf(acc[f][j] - m);
            acc[f][j] = e;
            ssum += e;
        }
#pragma unroll
        for (int off = 8; off > 0; off >>= 1) ssum += __shfl_xor(ssum, off);
        float inv = 1.0f / ssum;
        float* ap = alpha + ((size_t)bh * 512 + x) * 512 + li;
#pragma unroll
        for (int f = 0; f < 32; ++f) ap[f * 16] = acc[f][j] * inv;
    }
}

// ---------------------------------------------------------------------------
// PV MFMA: ao[b,x,h,d] fp32 = sum_y alpha[bh,x,y] * v[b,y,h,d].
// Block = (b,h, 128 x-rows), 4 waves; K=512 in 64-col tiles; alpha reg-staged
// to bf16 LDS, V staged from pre-transposed vT via GLL.
// ---------------------------------------------------------------------------
__global__ __launch_bounds__(256)
void pv_mfma_kernel(const float* __restrict__ alpha,
                    const unsigned short* __restrict__ vT,
                    float* __restrict__ ao)
{
    const int bh = blockIdx.y;
    const int b = bh >> 4, h = bh & 15;
    const int x0 = blockIdx.x * 128;
    const int tid = threadIdx.x;
    const int w = tid >> 6, lane = tid & 63;

    __shared__ unsigned short Ps[128 * 64];
    __shared__ unsigned short Vs[64 * 64];

    f32x4 acc[2][4];
#pragma unroll
    for (int m = 0; m < 2; ++m)
#pragma unroll
        for (int n = 0; n < 4; ++n) acc[m][n] = (f32x4){0.f, 0.f, 0.f, 0.f};

    const int sr = lane >> 3;
    const int sc = ((lane & 7) ^ sr) * 8;
    const int kof = (lane >> 4) * 8;

    for (int yt = 0; yt < 8; ++yt) {
        __syncthreads();
        // stage Vs: rows d (64), cols y_local (64), from vT[bh, d, yt*64+..]
#pragma unroll
        for (int i = 0; i < 2; ++i) {
            int c = w * 2 + i;
            GLL16(vT + ((size_t)bh * 64 + c * 8 + sr) * 512 + yt * 64 + sc, Vs + c * 512);
        }
        // stage Ps: 128 rows x 64 y, fp32->bf16, swizzled ds_write
#pragma unroll
        for (int i = 0; i < 4; ++i) {
            int idx = tid + i * 256;
            int r = idx >> 3, y8 = idx & 7;
            const float* src = alpha + ((size_t)bh * 512 + x0 + r) * 512 + yt * 64 + y8 * 8;
            float4 f0 = *(const float4*)src;
            float4 f1 = *(const float4*)(src + 4);
            ushort o[8] = {f2bf(f0.x), f2bf(f0.y), f2bf(f0.z), f2bf(f0.w),
                           f2bf(f1.x), f2bf(f1.y), f2bf(f1.z), f2bf(f1.w)};
            *(us8*)&Ps[r * 64 + ((y8 ^ (r & 7)) << 3)] = *(us8*)o;
        }
        __syncthreads();

        bf16x8 af[2][2], bf[2];
#pragma unroll
        for (int rf = 0; rf < 2; ++rf) {
            int arow = w * 32 + rf * 16 + (lane & 15);
            af[rf][0] = ldsfrag64(Ps, arow, kof);
            af[rf][1] = ldsfrag64(Ps, arow, kof + 32);
        }
#pragma unroll
        for (int cf = 0; cf < 4; ++cf) {
            int brow = cf * 16 + (lane & 15);
            bf[0] = ldsfrag64(Vs, brow, kof);
            bf[1] = ldsfrag64(Vs, brow, kof + 32);
#pragma unroll
            for (int rf = 0; rf < 2; ++rf) {
                acc[rf][cf] = __builtin_amdgcn_mfma_f32_16x16x32_bf16(af[rf][0], bf[0], acc[rf][cf], 0, 0, 0);
                acc[rf][cf] = __builtin_amdgcn_mfma_f32_16x16x32_bf16(af[rf][1], bf[1], acc[rf][cf], 0, 0, 0);
            }
        }
    }

    const int g = lane >> 4, li = lane & 15;
#pragma unroll
    for (int rf = 0; rf < 2; ++rf)
#pragma unroll
        for (int cf = 0; cf < 4; ++cf)
#pragma unroll
            for (int j = 0; j < 4; ++j) {
                int row = x0 + w * 32 + rf * 16 + g * 4 + j;
                int d = cf * 16 + li;
                ao[((size_t)(b * 512 + row)) * 1024 + h * 64 + d] = acc[rf][cf][j];
            }
}

// ---------------------------------------------------------------------------
extern "C" void kernel_launch(void* const* d_in, const int* in_sizes, int n_in,
                              void* d_out, int out_size, void* d_ws, size_t ws_size,
                              hipStream_t stream)
{
    const float* x       = (const float*)d_in[0];
    const int*   lengths = (const int*)d_in[1];
    const float* Wq      = (const float*)d_in[2];
    const float* Wk      = (const float*)d_in[3];
    const float* Wv      = (const float*)d_in[4];
    const float* Wo      = (const float*)d_in[5];
    const float* pl      = (const float*)d_in[6];
    const float* nq      = (const float*)d_in[7];
    const float* nk      = (const float*)d_in[8];
    const float* nv      = (const float*)d_in[9];
    const float* no      = (const float*)d_in[10];

    float* outp   = (float*)d_out;
    float* alphaF = outp + (size_t)M_ * D_;             // [B,H,S,S]

    // ws: qb,kb,vb,vT (bf16, 33.55MB each) + aof (fp32, 67.1MB) = 201.3MB
    unsigned short* qb = (unsigned short*)d_ws;
    unsigned short* kb = qb + (size_t)M_ * HD_;
    unsigned short* vb = kb + (size_t)M_ * HD_;
    unsigned short* vT = vb + (size_t)M_ * HD_;
    float*          aof = (float*)(vT + (size_t)M_ * HD_);
    unsigned short* Ao  = qb;                           // qb dead after attn
    unsigned short* WTo = kb;                           // kb dead after attn

    // bf16 staging in the alpha region (dead until attn writes it)
    unsigned short* WTq = (unsigned short*)(alphaF);
    unsigned short* WTk = (unsigned short*)(alphaF + 524288);
    unsigned short* WTv = (unsigned short*)(alphaF + 1048576);
    unsigned short* Aq  = (unsigned short*)(alphaF + 1572864);
    unsigned short* Ak  = (unsigned short*)(alphaF + 9961472);
    unsigned short* Av  = (unsigned short*)(alphaF + 18350080);

    dim3 wgrid(16, 16), blk(256);
    wcast_t_kernel<<<wgrid, blk, 0, stream>>>(Wq, WTq);
    wcast_t_kernel<<<wgrid, blk, 0, stream>>>(Wk, WTk);
    wcast_t_kernel<<<wgrid, blk, 0, stream>>>(Wv, WTv);

    cd_cast3_kernel<<<8192, blk, 0, stream>>>(x, nq, nk, nv, pl, Aq, Ak, Av);

    gemm_bf16_kernel<false, true><<<1024, blk, 0, stream>>>(Aq, WTq, qb);
    gemm_bf16_kernel<false, true><<<1024, blk, 0, stream>>>(Ak, WTk, kb);
    gemm_bf16_kernel<false, true><<<1024, blk, 0, stream>>>(Av, WTv, vb);

    vtrans_kernel<<<dim3(4, 512), blk, 0, stream>>>(vb, vT);

    attn_mfma_kernel<<<dim3(8, 512), blk, 0, stream>>>(qb, kb, lengths, alphaF);

    wcast_t_kernel<<<wgrid, blk, 0, stream>>>(Wo, WTo);

    pv_mfma_kernel<<<dim3(4, 512), blk, 0, stream>>>(alphaF, vT, aof);

    cd_cast1_kernel<<<8192, blk, 0, stream>>>(aof, no, pl + 3, Ao);

    gemm_bf16_kernel<true, false><<<1024, blk, 0, stream>>>(Ao, WTo, outp);
}